// Round 1
// 4130.984 us; speedup vs baseline: 1.2962x; 1.2962x over previous
//
#include <hip/hip_runtime.h>
#include <stdint.h>

#define TT 512
#define BSZ 128
#define NN 512
#define ROWS 4   // rows per group
// 32 groups x 8 blocks; block (g,i) owns j-slice [64*i, 64*i+64) for rows [4g,4g+4)

typedef _Float16 h2 __attribute__((ext_vector_type(2)));
typedef _Float16 h8 __attribute__((ext_vector_type(8)));

__device__ __forceinline__ float sigmoidf_(float x) {
    return 1.0f / (1.0f + __expf(-x));
}

#define H2P(v, i) __builtin_shufflevector((v), (v), 2 * (i), 2 * (i) + 1)

#define DOT8(acc, w, a)                                                   \
    do {                                                                  \
        acc = __builtin_amdgcn_fdot2(H2P(w, 0), H2P(a, 0), acc, false);   \
        acc = __builtin_amdgcn_fdot2(H2P(w, 1), H2P(a, 1), acc, false);   \
        acc = __builtin_amdgcn_fdot2(H2P(w, 2), H2P(a, 2), acc, false);   \
        acc = __builtin_amdgcn_fdot2(H2P(w, 3), H2P(a, 3), acc, false);   \
    } while (0)

#define DOT32(s, W, a0, a1, a2, a3)                                       \
    do { DOT8(s, W##0, a0); DOT8(s, W##1, a1);                            \
         DOT8(s, W##2, a2); DOT8(s, W##3, a3); } while (0)

__device__ __forceinline__ uint32_t pkf16(float a, float b) {
    h2 p; p[0] = (_Float16)a; p[1] = (_Float16)b;
    return __builtin_bit_cast(uint32_t, p);
}

// MALL-coherent (L1+L2 bypass) store / load: the inter-block exchange path.
__device__ __forceinline__ void st_u32_sc(uint32_t* p, uint32_t v) {
    asm volatile("global_store_dword %0, %1, off sc0 sc1" :: "v"(p), "v"(v) : "memory");
}
__device__ __forceinline__ uint32_t ld_u32_sc(const uint32_t* p) {
    uint32_t v;
    asm volatile("global_load_dword %0, %1, off sc0 sc1\n\ts_waitcnt vmcnt(0)"
                 : "=v"(v) : "v"(p) : "memory");
    return v;
}

// Issue 4x b128 gather of one row's 32-f16 chunk (64B) from MALL, no wait.
#define GATHER_ROW(d0, d1, d2, d3, p)                                         \
    asm volatile("global_load_dwordx4 %0, %4, off sc0 sc1\n\t"                \
                 "global_load_dwordx4 %1, %4, off offset:16 sc0 sc1\n\t"      \
                 "global_load_dwordx4 %2, %4, off offset:32 sc0 sc1\n\t"      \
                 "global_load_dwordx4 %3, %4, off offset:48 sc0 sc1"          \
                 : "=&v"(d0), "=&v"(d1), "=&v"(d2), "=&v"(d3) : "v"(p))

#define VMWAIT(n)                                                             \
    do { asm volatile("s_waitcnt vmcnt(" #n ")" ::: "memory");                \
         __builtin_amdgcn_sched_barrier(0); } while (0)

// load 8 strided f32 weights -> one h8 (column jg, rows o..o+7 of a [k][j] matrix)
#define LDW(dst, p, o)                                                        \
    do { h8 v_;                                                               \
        _Pragma("unroll")                                                     \
        for (int e_ = 0; e_ < 8; ++e_)                                        \
            v_[e_] = (_Float16)(p)[(size_t)((o) + e_) * NN];                  \
        dst = v_; } while (0)

// ---------- prep 1: ca3drive = ca3 @ wca3ca1  (T x N), fp32 ----------
__global__ void prep_ca3drive(const float* __restrict__ wca3ca1,
                              const int* __restrict__ ca3order,
                              float* __restrict__ drive) {
    __shared__ float ca3_sh[NN];
    const int t = blockIdx.x;
    const int j = threadIdx.x;
    int ord = ca3order[j];
    float center = -51.2f + (614.4f / 511.0f) * (float)ord;
    float d = center - (float)t;
    ca3_sh[j] = __expf(-(d * d) * 0.02f);
    __syncthreads();
    float acc = 0.0f;
#pragma unroll 8
    for (int c = 0; c < NN; ++c) {
        acc = fmaf(ca3_sh[c], wca3ca1[c * NN + j], acc);
    }
    drive[t * NN + j] = acc;
}

// ---------- prep 2: seed ec3 exchange buffer with f16(ec3_last) ----------
__global__ void prep_xch(const float* __restrict__ e3l, uint32_t* __restrict__ xe3u) {
    int b = blockIdx.x, j = threadIdx.x;   // 128 x 256
    float lo = e3l[b * NN + 2 * j];
    float hi = e3l[b * NN + 2 * j + 1];
    st_u32_sc(xe3u + b * 256 + j, pkf16(lo, hi));
}

// ---------- main: weight-stationary groups of 8 blocks ----------
__global__ __launch_bounds__(1024, 4) void rnn_main(
    const float* __restrict__ ec3input,
    const float* __restrict__ ec3_last,
    const float* __restrict__ ec5_last,
    const float* __restrict__ ca1bias,
    const float* __restrict__ wec3ca1,   // (N,N) [k][j] f32
    const float* __restrict__ wca1ec5,   // (N,N) [k][j] f32
    const int*   __restrict__ mask,
    const float* __restrict__ drive_all, // (T,N) f32
    uint32_t* __restrict__ xe3u,         // [128][256] f16-pairs exchange
    uint32_t* __restrict__ xca1u,        // [128][256]
    uint32_t* __restrict__ flags,        // [32 groups][32]: [0..7]=A(ca1), [8..15]=B(ec3)
    float* __restrict__ out)
{
    __shared__ float part[16][ROWS][64];

    const int tid  = threadIdx.x;
    const int lane = tid & 63;
    const int wv   = tid >> 6;      // wave 0..15
    const int pw   = wv >> 1;       // producer slice for this wave's k-chunk
    const int rp   = wv & 3;        // pointwise row (valid role only for tid<256)
    const int g    = blockIdx.x >> 3;
    const int i    = blockIdx.x & 7;
    const int R0   = g * ROWS;
    const int J0   = i * 64;
    const int jg   = J0 + lane;     // this thread's output column
    const int k0   = 32 * wv;       // this wave's k-chunk

    // ---- persistent weights in VGPRs: W[k0..k0+32)[jg] for both matrices ----
    h8 w1r0, w1r1, w1r2, w1r3, w2r0, w2r1, w2r2, w2r3;
    {
        const float* p1 = wec3ca1 + (size_t)k0 * NN + jg;
        const float* p2 = wca1ec5 + (size_t)k0 * NN + jg;
        LDW(w1r0, p1, 0);  LDW(w1r1, p1, 8);  LDW(w1r2, p1, 16); LDW(w1r3, p1, 24);
        LDW(w2r0, p2, 0);  LDW(w2r1, p2, 8);  LDW(w2r2, p2, 16); LDW(w2r3, p2, 24);
    }

    // ---- pointwise state (threads 0..255: wave rp = row, lane = column) ----
    const int rowp = R0 + rp;                       // always in-bounds (rp<=3)
    const size_t hbase = (size_t)rowp * TT * NN + jg;
    float ec3  = ec3_last[rowp * NN + jg];
    float ec5  = ec5_last[rowp * NN + jg];
    float ca1  = 0.0f;
    const float biasv = ca1bias[jg];

    float* out_e3h = out + (size_t)131072;
    float* out_e5h = out_e3h + (size_t)33554432;
    float* out_c1h = out_e5h + (size_t)33554432;
    float* out_e3  = out_c1h + (size_t)33554432;
    float* out_e5  = out_e3 + (size_t)65536;
    float* out_c1  = out_e5 + (size_t)65536;

    uint32_t* fA = flags + g * 32;      // ca1 slice counters
    uint32_t* fB = flags + g * 32 + 8;  // ec3 slice counters

    const uint32_t* pr_e3 = (const uint32_t*)xe3u  + R0 * 256 + (k0 >> 1);
    const uint32_t* pr_c1 = (const uint32_t*)xca1u + R0 * 256 + (k0 >> 1);

    for (int t = 0; t < TT; ++t) {
        const size_t ho = hbase + (size_t)t * NN;
        // early issue of pointwise inputs (consumed after the matvecs)
        float dr = 0.0f, x = 0.0f; int m = 0;
        if (tid < 256) {
            dr = drive_all[t * NN + jg];
            x  = ec3input[ho];
            m  = mask[ho];
        }

        // ================= matvec1: s1 = ec3 @ W1 (partial over k-chunk) ===
        if (pw != i) { while (ld_u32_sc(fB + pw) < (uint32_t)t) {} }
        asm volatile("" ::: "memory");
        {
            h8 A0, A1, A2, A3, B0, B1, B2, B3;
            GATHER_ROW(A0, A1, A2, A3, pr_e3);
            GATHER_ROW(B0, B1, B2, B3, pr_e3 + 256);
            float s0 = 0.f, s1 = 0.f, s2 = 0.f, s3 = 0.f;
            VMWAIT(4);
            DOT32(s0, w1r, A0, A1, A2, A3);
            GATHER_ROW(A0, A1, A2, A3, pr_e3 + 512);
            VMWAIT(4);
            DOT32(s1, w1r, B0, B1, B2, B3);
            GATHER_ROW(B0, B1, B2, B3, pr_e3 + 768);
            VMWAIT(4);
            DOT32(s2, w1r, A0, A1, A2, A3);
            VMWAIT(0);
            DOT32(s3, w1r, B0, B1, B2, B3);
            part[wv][0][lane] = s0; part[wv][1][lane] = s1;
            part[wv][2][lane] = s2; part[wv][3][lane] = s3;
        }
        __syncthreads();                                   // B1

        // ================= phase A: ca1, history, exchange =================
        if (tid < 256) {
            float s = 0.f;
#pragma unroll
            for (int q = 0; q < 16; ++q) s += part[q][rp][lane];
            float c1 = dr * (1.0f + sigmoidf_(s)) - biasv;
            c1 = fminf(fmaxf(c1, 0.0f), 1.0f);
            ca1 = c1;
            out_c1h[ho] = c1;
            float o = __shfl_down(c1, 1, 64);
            if (!(lane & 1))
                st_u32_sc(xca1u + rowp * 256 + (jg >> 1), pkf16(c1, o));
        }
        __syncthreads();                                   // B2 (stores drained)
        if (tid == 0) atomicAdd(fA + i, 1u);

        // ================= matvec2: s2 = ca1 @ W2 (partial over k-chunk) ===
        if (pw != i) { while (ld_u32_sc(fA + pw) < (uint32_t)(t + 1)) {} }
        asm volatile("" ::: "memory");
        {
            h8 A0, A1, A2, A3, B0, B1, B2, B3;
            GATHER_ROW(A0, A1, A2, A3, pr_c1);
            GATHER_ROW(B0, B1, B2, B3, pr_c1 + 256);
            float s0 = 0.f, s1 = 0.f, s2 = 0.f, s3 = 0.f;
            VMWAIT(4);
            DOT32(s0, w2r, A0, A1, A2, A3);
            GATHER_ROW(A0, A1, A2, A3, pr_c1 + 512);
            VMWAIT(4);
            DOT32(s1, w2r, B0, B1, B2, B3);
            GATHER_ROW(B0, B1, B2, B3, pr_c1 + 768);
            VMWAIT(4);
            DOT32(s2, w2r, A0, A1, A2, A3);
            VMWAIT(0);
            DOT32(s3, w2r, B0, B1, B2, B3);
            part[wv][0][lane] = s0; part[wv][1][lane] = s1;
            part[wv][2][lane] = s2; part[wv][3][lane] = s3;
        }
        __syncthreads();                                   // B3

        // ================= phase B: ec5, ec3, history, exchange ============
        if (tid < 256) {
            float s = 0.f;
#pragma unroll
            for (int q = 0; q < 16; ++q) s += part[q][rp][lane];
            ec5 += s;                                      // 10*TS = 1.0
            ec5 = 0.69f + 0.3f * sigmoidf_(4.0f * (ec5 - 0.3f));
            ec3 = ec5 * ec3 + 0.6f * (1.0f - ec3) * x;
            if (m) ec3 = 0.5f * ec3 + 0.3f;
            out_e3h[ho] = ec3;
            out_e5h[ho] = ec5;
            float o = __shfl_down(ec3, 1, 64);
            if (!(lane & 1))
                st_u32_sc(xe3u + rowp * 256 + (jg >> 1), pkf16(ec3, o));
        }
        __syncthreads();                                   // B4 (stores drained)
        if (tid == 0) atomicAdd(fB + i, 1u);
    }

    if (tid < 256) {
        out_e3[rowp * NN + jg] = ec3;
        out_e5[rowp * NN + jg] = ec5;
        out_c1[rowp * NN + jg] = ca1;
    }
}

// ---------- post: act[b][t][c] = ca1his[b][t][:] @ wca1act + actbias ----------
__global__ __launch_bounds__(256) void act_final(
    const float* __restrict__ c1h, const float* __restrict__ wca1act,
    const float* __restrict__ actbias, float* __restrict__ out_act)
{
    __shared__ float wa[2 * NN];
    for (int k = threadIdx.x; k < 2 * NN; k += 256) wa[k] = wca1act[k];
    __syncthreads();
    const int wid = blockIdx.x * 4 + (threadIdx.x >> 6);   // (b,t) flat
    const int l = threadIdx.x & 63;
    const float* src = c1h + (size_t)wid * NN;
    float s0 = 0.f, s1 = 0.f;
#pragma unroll
    for (int it = 0; it < 8; ++it) {
        int k = l + 64 * it;
        float v = src[k];
        s0 = fmaf(v, wa[2 * k], s0);
        s1 = fmaf(v, wa[2 * k + 1], s1);
    }
#pragma unroll
    for (int off = 32; off > 0; off >>= 1) {
        s0 += __shfl_down(s0, off, 64);
        s1 += __shfl_down(s1, off, 64);
    }
    if (l == 0) {
        out_act[(size_t)wid * 2 + 0] = s0 + actbias[0];
        out_act[(size_t)wid * 2 + 1] = s1 + actbias[1];
    }
}

// ---------- launch ----------
extern "C" void kernel_launch(void* const* d_in, const int* in_sizes, int n_in,
                              void* d_out, int out_size, void* d_ws, size_t ws_size,
                              hipStream_t stream) {
    const float* ec3input = (const float*)d_in[0];
    const float* ec3_last = (const float*)d_in[1];
    const float* ec5_last = (const float*)d_in[2];
    /* d_in[3] ca1_last unused */
    const float* ca1bias  = (const float*)d_in[4];
    const float* wca3ca1  = (const float*)d_in[5];
    const float* wec3ca1  = (const float*)d_in[6];
    const float* wca1ec5  = (const float*)d_in[7];
    const float* wca1act  = (const float*)d_in[8];
    const float* actbias  = (const float*)d_in[9];
    const int*   mask     = (const int*)d_in[10];
    const int*   ca3order = (const int*)d_in[11];
    float* outf = (float*)d_out;

    char* ws = (char*)d_ws;
    float*    drive = (float*)ws;                                // 1 MB
    uint32_t* xe3u  = (uint32_t*)(ws + (1 << 20));               // 128 KB
    uint32_t* xca1u = (uint32_t*)(ws + (1 << 20) + (128 << 10)); // 128 KB
    uint32_t* flags = (uint32_t*)(ws + (1 << 20) + (256 << 10)); // 4 KB

    float* c1h = outf + (size_t)131072 + 2 * (size_t)33554432;

    hipMemsetAsync(flags, 0, 32 * 32 * sizeof(uint32_t), stream);
    hipLaunchKernelGGL(prep_ca3drive, dim3(TT), dim3(NN), 0, stream,
                       wca3ca1, ca3order, drive);
    hipLaunchKernelGGL(prep_xch, dim3(BSZ), dim3(256), 0, stream, ec3_last, xe3u);
    hipLaunchKernelGGL(rnn_main, dim3(256), dim3(1024), 0, stream,
                       ec3input, ec3_last, ec5_last, ca1bias,
                       wec3ca1, wca1ec5, mask, drive,
                       xe3u, xca1u, flags, outf);
    hipLaunchKernelGGL(act_final, dim3(BSZ * TT / 4), dim3(256), 0, stream,
                       c1h, wca1act, actbias, outf);
}

// Round 2
// 3184.608 us; speedup vs baseline: 1.6814x; 1.2972x over previous
//
#include <hip/hip_runtime.h>
#include <stdint.h>

#define TT 512
#define BSZ 128
#define NN 512

typedef _Float16 h2 __attribute__((ext_vector_type(2)));
typedef _Float16 h8 __attribute__((ext_vector_type(8)));
typedef uint32_t u32x2 __attribute__((ext_vector_type(2)));

__device__ __forceinline__ float sigmoidf_(float x) {
    return 1.0f / (1.0f + __expf(-x));
}

#define H2P(v, i) __builtin_shufflevector((v), (v), 2 * (i), 2 * (i) + 1)

#define DOT8(acc, w, a)                                                   \
    do {                                                                  \
        acc = __builtin_amdgcn_fdot2(H2P(w, 0), H2P(a, 0), acc, false);   \
        acc = __builtin_amdgcn_fdot2(H2P(w, 1), H2P(a, 1), acc, false);   \
        acc = __builtin_amdgcn_fdot2(H2P(w, 2), H2P(a, 2), acc, false);   \
        acc = __builtin_amdgcn_fdot2(H2P(w, 3), H2P(a, 3), acc, false);   \
    } while (0)

__device__ __forceinline__ uint32_t pkf16(float a, float b) {
    h2 p; p[0] = (_Float16)a; p[1] = (_Float16)b;
    return __builtin_bit_cast(uint32_t, p);
}

// ---- tagged 8B exchange slot: (f16-pair, step-tag), MALL-coherent ----
__device__ __forceinline__ void storepair(u32x2* p, uint32_t pair, uint32_t tag) {
    u32x2 v; v.x = pair; v.y = tag;
    asm volatile("global_store_dwordx2 %0, %1, off sc0 sc1"
                 :: "v"(p), "v"(v) : "memory");
}

// poll until the whole wave's slots carry tag >= want; returns fresh pair
__device__ __forceinline__ uint32_t pollpair(const u32x2* p, uint32_t want) {
    u32x2 v;
    do {
        asm volatile("global_load_dwordx2 %0, %1, off sc0 sc1\n\t"
                     "s_waitcnt vmcnt(0)"
                     : "=v"(v) : "v"(p) : "memory");
    } while (!__all((int)(v.y >= want)));
    __builtin_amdgcn_sched_barrier(0);
    return v.x;
}

// poll the 16 per-wave LDS sequence flags until all >= seq
__device__ __forceinline__ void pollfl(volatile uint32_t* fl, uint32_t seq, int lane) {
    for (;;) {
        uint32_t v = (lane < 16) ? fl[lane] : seq;
        if (__all((int)(v >= seq))) break;
    }
    asm volatile("" ::: "memory");
    __builtin_amdgcn_sched_barrier(0);
}

// ---------- prep 1: ca3drive = ca3 @ wca3ca1  (T x N), fp32 ----------
__global__ void prep_ca3drive(const float* __restrict__ wca3ca1,
                              const int* __restrict__ ca3order,
                              float* __restrict__ drive) {
    __shared__ float ca3_sh[NN];
    const int t = blockIdx.x;
    const int j = threadIdx.x;
    int ord = ca3order[j];
    float center = -51.2f + (614.4f / 511.0f) * (float)ord;
    float d = center - (float)t;
    ca3_sh[j] = __expf(-(d * d) * 0.02f);
    __syncthreads();
    float acc = 0.0f;
#pragma unroll 8
    for (int c = 0; c < NN; ++c) {
        acc = fmaf(ca3_sh[c], wca3ca1[c * NN + j], acc);
    }
    drive[t * NN + j] = acc;
}

// ---------- prep 2: seed tagged ec3 exchange with f16(ec3_last), tag 0 ----------
__global__ void prep_xch(const float* __restrict__ e3l, u32x2* __restrict__ xe3t) {
    int b = blockIdx.x, j = threadIdx.x;   // 128 x 256
    float lo = e3l[b * NN + 2 * j];
    float hi = e3l[b * NN + 2 * j + 1];
    storepair(xe3t + b * 256 + j, pkf16(lo, hi), 0u);
}

// ---------- main: weight-stationary, barrier-free tagged pipeline ----------
// 32 groups x 8 blocks. Block (g,i): rows [4g,4g+4), j-slice [64i,64i+64).
// Wave wv: matvec partial for k-chunk [32wv,32wv+32), all 64 j (lane=j),
//          pointwise for row (wv&3), 16 columns [(wv>>2)*16, +16) (lanes 0-15).
__global__ __launch_bounds__(1024, 4) void rnn_main(
    const float* __restrict__ ec3input,
    const float* __restrict__ ec3_last,
    const float* __restrict__ ec5_last,
    const float* __restrict__ ca1bias,
    const float* __restrict__ wec3ca1,   // (N,N) [k][j] f32
    const float* __restrict__ wca1ec5,   // (N,N) [k][j] f32
    const int*   __restrict__ mask,
    const float* __restrict__ drive_all, // (T,N) f32
    u32x2* __restrict__ xe3t,            // [128][256] tagged pairs
    u32x2* __restrict__ xca1t,           // [128][256] tagged pairs
    float* __restrict__ out)
{
    __shared__ float part[2][16][4][64];             // 32 KB ping-pong partials
    __shared__ __align__(16) uint32_t xb[16][64];    // 4 KB wave-private bounce
    __shared__ uint32_t fl[16];                      // per-wave sequence flags

    const int tid  = threadIdx.x;
    const int lane = tid & 63;
    const int wv   = tid >> 6;
    const int g    = blockIdx.x >> 3;
    const int i    = blockIdx.x & 7;
    const int R0   = g * 4;
    const int J0   = i * 64;
    const int jg   = J0 + lane;
    const int k0   = 32 * wv;

    // ---- persistent f16 weights in VGPRs: both matrices, k-chunk x column jg ----
    h8 w1[4], w2[4];
#pragma unroll
    for (int it = 0; it < 4; ++it) {
        h8 a, b;
#pragma unroll
        for (int e = 0; e < 8; ++e) {
            a[e] = (_Float16)wec3ca1[(size_t)(k0 + 8 * it + e) * NN + jg];
            b[e] = (_Float16)wca1ec5[(size_t)(k0 + 8 * it + e) * NN + jg];
        }
        w1[it] = a; w2[it] = b;
    }

    // ---- pointwise role (lanes 0-15 of each wave) ----
    const int  rr   = wv & 3;
    const int  jo   = (wv >> 2) * 16 + lane;   // meaningful for lane<16
    const int  rowp = R0 + rr;
    const bool pact = lane < 16;
    float ec3 = 0.f, ec5 = 0.f, ca1 = 0.f, biasv = 0.f;
    if (pact) {
        ec3   = ec3_last[rowp * NN + J0 + jo];
        ec5   = ec5_last[rowp * NN + J0 + jo];
        biasv = ca1bias[J0 + jo];
    }

    float* out_e3h = out + (size_t)131072;
    float* out_e5h = out_e3h + (size_t)33554432;
    float* out_c1h = out_e5h + (size_t)33554432;
    float* out_e3  = out_c1h + (size_t)33554432;
    float* out_e5  = out_e3 + (size_t)65536;
    float* out_c1  = out_e5 + (size_t)65536;

    // gather addresses: lane -> (row lane>>4, pair k0/2 + (lane&15))
    const u32x2* gx_e3 = xe3t  + (size_t)(R0 + (lane >> 4)) * 256 + (k0 >> 1) + (lane & 15);
    const u32x2* gx_c1 = xca1t + (size_t)(R0 + (lane >> 4)) * 256 + (k0 >> 1) + (lane & 15);
    // pointwise tagged-store addresses (even lanes < 16)
    u32x2* sx_c1 = xca1t + (size_t)rowp * 256 + ((J0 + jo) >> 1);
    u32x2* sx_e3 = xe3t  + (size_t)rowp * 256 + ((J0 + jo) >> 1);

    if (tid < 16) fl[tid] = 0;
    __syncthreads();

    for (int t = 0; t < TT; ++t) {
        const size_t ho = ((size_t)rowp * TT + t) * NN + J0 + jo;
        // early-issue pointwise inputs (drained by first poll's vmcnt(0))
        float dr = 0.f, x = 0.f; int m = 0;
        if (pact) {
            dr = drive_all[t * NN + J0 + jo];
            x  = ec3input[ho];
            m  = mask[ho];
        }

        // ===== matvec1 partial: s1 = ec3 @ W1 over own k-chunk, 4 rows =====
        {
            uint32_t pr = pollpair(gx_e3, (uint32_t)t);
            xb[wv][lane] = pr;
            asm volatile("s_waitcnt lgkmcnt(0)" ::: "memory");
            __builtin_amdgcn_sched_barrier(0);
            float s0 = 0.f, s1 = 0.f, s2 = 0.f, s3 = 0.f;
#pragma unroll
            for (int it = 0; it < 4; ++it) {
                h8 a0 = *(const h8*)&xb[wv][ 0 + it * 4];
                h8 a1 = *(const h8*)&xb[wv][16 + it * 4];
                h8 a2 = *(const h8*)&xb[wv][32 + it * 4];
                h8 a3 = *(const h8*)&xb[wv][48 + it * 4];
                DOT8(s0, w1[it], a0); DOT8(s1, w1[it], a1);
                DOT8(s2, w1[it], a2); DOT8(s3, w1[it], a3);
            }
            part[0][wv][0][lane] = s0; part[0][wv][1][lane] = s1;
            part[0][wv][2][lane] = s2; part[0][wv][3][lane] = s3;
            asm volatile("s_waitcnt lgkmcnt(0)" ::: "memory");
            if (lane == 0) fl[wv] = 2u * (uint32_t)t + 1u;
        }

        // ===== phase A: ca1 pointwise for own 16 outputs =====
        pollfl(fl, 2u * (uint32_t)t + 1u, lane);
        if (pact) {
            float s = 0.f;
#pragma unroll
            for (int q = 0; q < 16; ++q) s += part[0][q][rr][jo];
            float c1 = dr * (1.0f + sigmoidf_(s)) - biasv;
            c1 = fminf(fmaxf(c1, 0.0f), 1.0f);
            ca1 = c1;
            out_c1h[ho] = c1;
            float o = __shfl_down(c1, 1, 64);
            if (!(lane & 1)) storepair(sx_c1, pkf16(c1, o), (uint32_t)t + 1u);
        }

        // ===== matvec2 partial: s2 = ca1 @ W2 over own k-chunk, 4 rows =====
        {
            uint32_t pr = pollpair(gx_c1, (uint32_t)t + 1u);
            xb[wv][lane] = pr;
            asm volatile("s_waitcnt lgkmcnt(0)" ::: "memory");
            __builtin_amdgcn_sched_barrier(0);
            float s0 = 0.f, s1 = 0.f, s2 = 0.f, s3 = 0.f;
#pragma unroll
            for (int it = 0; it < 4; ++it) {
                h8 a0 = *(const h8*)&xb[wv][ 0 + it * 4];
                h8 a1 = *(const h8*)&xb[wv][16 + it * 4];
                h8 a2 = *(const h8*)&xb[wv][32 + it * 4];
                h8 a3 = *(const h8*)&xb[wv][48 + it * 4];
                DOT8(s0, w2[it], a0); DOT8(s1, w2[it], a1);
                DOT8(s2, w2[it], a2); DOT8(s3, w2[it], a3);
            }
            part[1][wv][0][lane] = s0; part[1][wv][1][lane] = s1;
            part[1][wv][2][lane] = s2; part[1][wv][3][lane] = s3;
            asm volatile("s_waitcnt lgkmcnt(0)" ::: "memory");
            if (lane == 0) fl[wv] = 2u * (uint32_t)t + 2u;
        }

        // ===== phase B: ec5/ec3 pointwise for own 16 outputs =====
        pollfl(fl, 2u * (uint32_t)t + 2u, lane);
        if (pact) {
            float s = 0.f;
#pragma unroll
            for (int q = 0; q < 16; ++q) s += part[1][q][rr][jo];
            ec5 += s;                                  // 10*TS = 1.0
            ec5 = 0.69f + 0.3f * sigmoidf_(4.0f * (ec5 - 0.3f));
            ec3 = ec5 * ec3 + 0.6f * (1.0f - ec3) * x;
            if (m) ec3 = 0.5f * ec3 + 0.3f;
            out_e3h[ho] = ec3;
            out_e5h[ho] = ec5;
            float o = __shfl_down(ec3, 1, 64);
            if (!(lane & 1)) storepair(sx_e3, pkf16(ec3, o), (uint32_t)t + 1u);
        }
    }

    if (pact) {
        out_e3[rowp * NN + J0 + jo] = ec3;
        out_e5[rowp * NN + J0 + jo] = ec5;
        out_c1[rowp * NN + J0 + jo] = ca1;
    }
}

// ---------- post: act[b][t][c] = ca1his[b][t][:] @ wca1act + actbias ----------
__global__ __launch_bounds__(256) void act_final(
    const float* __restrict__ c1h, const float* __restrict__ wca1act,
    const float* __restrict__ actbias, float* __restrict__ out_act)
{
    __shared__ float wa[2 * NN];
    for (int k = threadIdx.x; k < 2 * NN; k += 256) wa[k] = wca1act[k];
    __syncthreads();
    const int wid = blockIdx.x * 4 + (threadIdx.x >> 6);   // (b,t) flat
    const int l = threadIdx.x & 63;
    const float* src = c1h + (size_t)wid * NN;
    float s0 = 0.f, s1 = 0.f;
#pragma unroll
    for (int it = 0; it < 8; ++it) {
        int k = l + 64 * it;
        float v = src[k];
        s0 = fmaf(v, wa[2 * k], s0);
        s1 = fmaf(v, wa[2 * k + 1], s1);
    }
#pragma unroll
    for (int off = 32; off > 0; off >>= 1) {
        s0 += __shfl_down(s0, off, 64);
        s1 += __shfl_down(s1, off, 64);
    }
    if (l == 0) {
        out_act[(size_t)wid * 2 + 0] = s0 + actbias[0];
        out_act[(size_t)wid * 2 + 1] = s1 + actbias[1];
    }
}

// ---------- launch ----------
extern "C" void kernel_launch(void* const* d_in, const int* in_sizes, int n_in,
                              void* d_out, int out_size, void* d_ws, size_t ws_size,
                              hipStream_t stream) {
    const float* ec3input = (const float*)d_in[0];
    const float* ec3_last = (const float*)d_in[1];
    const float* ec5_last = (const float*)d_in[2];
    /* d_in[3] ca1_last unused */
    const float* ca1bias  = (const float*)d_in[4];
    const float* wca3ca1  = (const float*)d_in[5];
    const float* wec3ca1  = (const float*)d_in[6];
    const float* wca1ec5  = (const float*)d_in[7];
    const float* wca1act  = (const float*)d_in[8];
    const float* actbias  = (const float*)d_in[9];
    const int*   mask     = (const int*)d_in[10];
    const int*   ca3order = (const int*)d_in[11];
    float* outf = (float*)d_out;

    char* ws = (char*)d_ws;
    float* drive = (float*)ws;                                  // 1 MB
    u32x2* xe3t  = (u32x2*)(ws + (1 << 20));                    // 256 KB tagged
    u32x2* xca1t = (u32x2*)(ws + (1 << 20) + (256 << 10));      // 256 KB tagged

    float* c1h = outf + (size_t)131072 + 2 * (size_t)33554432;

    hipMemsetAsync(xca1t, 0, 128 * 256 * 8, stream);
    hipLaunchKernelGGL(prep_ca3drive, dim3(TT), dim3(NN), 0, stream,
                       wca3ca1, ca3order, drive);
    hipLaunchKernelGGL(prep_xch, dim3(BSZ), dim3(256), 0, stream, ec3_last, xe3t);
    hipLaunchKernelGGL(rnn_main, dim3(256), dim3(1024), 0, stream,
                       ec3input, ec3_last, ec5_last, ca1bias,
                       wec3ca1, wca1ec5, mask, drive,
                       xe3t, xca1t, outf);
    hipLaunchKernelGGL(act_final, dim3(BSZ * TT / 4), dim3(256), 0, stream,
                       c1h, wca1act, actbias, outf);
}